// Round 15
// baseline (76.372 us; speedup 1.0000x reference)
//
#include <hip/hip_runtime.h>
#include <math.h>

#define Bb 32
#define Tt 131072
#define SEG 2048          // segment per pass (lookback and emit both 2048)
#define NCB (Tt / SEG)    // 64 chunks per row -> grid 2048 (8 blocks/CU)
#define TPB 256
#define PT 8              // SEG / TPB

// padded LDS index: +1 float per 8 -> inter-lane stride 9 (conflict-free)
#define XSP ((SEG + 64) + ((SEG + 64) >> 3) + 8)

__device__ __forceinline__ float sigmoidf_(float v) { return 1.0f / (1.0f + __expf(-v)); }
__device__ __forceinline__ float softplusf_(float z) {
  return fmaxf(z, 0.0f) + __logf(1.0f + __expf(-fabsf(z)));
}
__device__ __forceinline__ float dgainf_(float sa) {
  return fminf(1000.0f, __fdividef(1.0f, sqrtf(sa) + 1e-8f));
}
__device__ __forceinline__ float pow8f_(float r) {
  float r2 = r * r, r4 = r2 * r2;
  return r4 * r4;
}

// 4-wave block scan of affine maps s -> m*s + b (thread order = time order).
__device__ __forceinline__ void affine_scan4(
    float m, float b, float& Mex, float& Bex, float& Btot, float* smem) {
  const int lane = threadIdx.x & 63;
  const int wave = threadIdx.x >> 6;
  float mi = m, bi = b;
#pragma unroll
  for (int d = 1; d < 64; d <<= 1) {
    float mp = __shfl_up(mi, d);
    float bp = __shfl_up(bi, d);
    if (lane >= d) { bi = fmaf(mi, bp, bi); mi *= mp; }
  }
  __syncthreads();
  if (lane == 63) { smem[2 * wave] = mi; smem[2 * wave + 1] = bi; }
  __syncthreads();
  float Mw = 1.0f, Bw = 0.0f;
#pragma unroll
  for (int wv = 0; wv < 3; ++wv) {
    if (wv < wave) {
      float mw = smem[2 * wv], bw = smem[2 * wv + 1];
      Bw = fmaf(mw, Bw, bw);
      Mw = mw * Mw;
    }
  }
  float mep = __shfl_up(mi, 1);
  float bep = __shfl_up(bi, 1);
  float me = (lane == 0) ? 1.0f : mep;
  float be = (lane == 0) ? 0.0f : bep;
  Mex = me * Mw;
  Bex = fmaf(me, Bw, be);
  Btot = fmaf(mi, Bw, bi);   // block-inclusive total on thread TPB-1
}

// One channel: stage RAW x to LDS (+1/8 pad), grab own 8 x into regs,
// 64-tap conv(x^2) with 8-wide group prefetch (R12-proven core).
__device__ __forceinline__ void conv8(
    const float* __restrict__ xr, const float* __restrict__ wc, const float cwc,
    float* xs, float (&xo)[PT], float (&pacc)[PT], const int t0, const int pb) {
  for (int i = threadIdx.x; i < (SEG + 64) / 4; i += TPB) {
    const int g = t0 - 64 + 4 * i;   // raw lds[j] = x[t0-64+j]
    float4 v = make_float4(0.f, 0.f, 0.f, 0.f);
    if (g >= 0) v = *(const float4*)(xr + g);
    const int j = 4 * i;
    xs[j + 0 + ((j + 0) >> 3)] = v.x;
    xs[j + 1 + ((j + 1) >> 3)] = v.y;
    xs[j + 2 + ((j + 2) >> 3)] = v.z;
    xs[j + 3 + ((j + 3) >> 3)] = v.w;
  }
  __syncthreads();
#pragma unroll
  for (int i = 0; i < PT; ++i) xo[i] = xs[pb + 72 + i];   // own raw x (slots 64+8t..)
  float win[8];
#pragma unroll
  for (int i = 0; i < 8; ++i) {
    float u = xs[pb + 1 + i + ((1 + i) >> 3)];
    win[i] = u * u;
  }
#pragma unroll 1
  for (int g = 0; g < 8; ++g) {
    const int rb = pb + 9 * g + 10;   // padded addr of raw slot 8g+9
    float nxt[8];
#pragma unroll
    for (int j = 0; j < 8; ++j) {
      if (g * 8 + j < 63) {
        float u = xs[rb + j + ((j + 1) >> 3)];
        nxt[j] = u * u;
      }
    }
#pragma unroll
    for (int k2 = 0; k2 < 8; ++k2) {
      const float wk = wc[g * 8 + k2] * cwc;   // uniform -> scalar load
#pragma unroll
      for (int i = 0; i < PT; ++i)
        pacc[i] = fmaf(wk, win[(k2 + i) & 7], pacc[i]);
      win[k2] = nxt[k2];   // register move
    }
  }
}

// kA: per 2048-chunk: 2048 lookback (zero-init, decay-sufficient: r1^2048~1e-46,
// r2^2048~3.5e-5 — R12-validated error) + emitted 2048 segment.
__global__ __launch_bounds__(TPB, 3) void k_gain(
    const float* __restrict__ x, const float* __restrict__ conv_w,
    const float* __restrict__ combine_w, const float* __restrict__ combine_b,
    const float* __restrict__ la_att, const float* __restrict__ la_rel,
    float* __restrict__ pg, float* __restrict__ partials) {
  __shared__ float xs[XSP];
  __shared__ float ssm[8];
  __shared__ float bc[3];
  __shared__ float red[4][4];
  const int b = blockIdx.x / NCB;
  const int ch = blockIdx.x % NCB;
  const int tc = ch * SEG;
  const int pb = 9 * (int)threadIdx.x;   // padded base of raw 8*tid
  const float a1 = sigmoidf_(la_att[0]); const float r1 = 1.0f - a1;
  const float a2 = sigmoidf_(la_rel[0]); const float r2 = 1.0f - a2;
  const float rs1 = __expf((float)SEG * __logf(r1));   // r1^2048 (underflows)
  const float rs2 = __expf((float)SEG * __logf(r2));   // r2^2048 ~ 3.5e-5
  const float cb = combine_b[0];
  const float cw0 = combine_w[0], cw1 = combine_w[1];
  const float* xr0 = x + (size_t)(b * 2 + 0) * Tt;
  const float* xr1 = x + (size_t)(b * 2 + 1) * Tt;
  float s1 = 0.0f, s2 = 0.0f;    // EMA states entering current segment
  float st0 = 0.f, sq0 = 0.f, st1 = 0.f, sq1 = 0.f;

  const int s_begin = (ch == 0) ? 0 : -1;
#pragma unroll 1
  for (int s = s_begin; s <= 0; ++s) {
    const int t0 = tc + s * SEG;
    const bool emit = (s == 0);
    float pacc[PT];
#pragma unroll
    for (int i = 0; i < PT; ++i) pacc[i] = cb;
    float xa[PT], xb[PT];
    conv8(xr0, conv_w, cw0, xs, xa, pacc, t0, pb);
    __syncthreads();   // ch0 window reads done before ch1 staging overwrites
    conv8(xr1, conv_w + 64, cw1, xs, xb, pacc, t0, pb);
    float pv[PT];
#pragma unroll
    for (int i = 0; i < PT; ++i) pv[i] = softplusf_(pacc[i]) + 1e-8f;
    const bool init0 = (ch == 0) && emit;
    if (init0 && threadIdx.x == 0) bc[2] = pv[0];   // p[b,0]; visible after scan syncs
    float e1 = 0.0f;
#pragma unroll
    for (int i = 0; i < PT; ++i) e1 = fmaf(a1, pv[i], r1 * e1);
    float Mex, Bex, Bt;
    affine_scan4(pow8f_(r1), e1, Mex, Bex, Bt, ssm);
    if (init0) { s1 = bc[2]; s2 = dgainf_(bc[2]); }   // ref init: y[-1]=p0, g[-1]=dg(p0)
    float y = fmaf(Mex, s1, Bex);
    float dg[PT];
    float e2 = 0.0f;
#pragma unroll
    for (int i = 0; i < PT; ++i) {
      y = fmaf(a1, pv[i], r1 * y);
      dg[i] = dgainf_(y);
      e2 = fmaf(a2, dg[i], r2 * e2);
    }
    const float Bt1 = Bt;
    affine_scan4(pow8f_(r2), e2, Mex, Bex, Bt, ssm);
    if (threadIdx.x == TPB - 1) { bc[0] = Bt1; bc[1] = Bt; }
    if (emit) {
      float g = fmaf(Mex, s2, Bex);
      float gv[PT];
#pragma unroll
      for (int i = 0; i < PT; ++i) { g = fmaf(a2, dg[i], r2 * g); gv[i] = g; }
      float* prow = pg + (size_t)b * Tt + t0 + (int)threadIdx.x * PT;
#pragma unroll
      for (int i = 0; i < PT; i += 4)
        *(float4*)(prow + i) = make_float4(gv[i], gv[i + 1], gv[i + 2], gv[i + 3]);
#pragma unroll
      for (int i = 0; i < PT; ++i) {
        float u0 = xa[i] * gv[i]; st0 += u0; sq0 = fmaf(u0, u0, sq0);
        float u1 = xb[i] * gv[i]; st1 += u1; sq1 = fmaf(u1, u1, sq1);
      }
    }
    __syncthreads();   // bc[0..1] published; xs reads done before next staging
    s1 = fmaf(rs1, s1, bc[0]);
    s2 = fmaf(rs2, s2, bc[1]);
  }
  // block stats reduce -> partials[blockIdx.x]
#pragma unroll
  for (int d = 32; d > 0; d >>= 1) {
    st0 += __shfl_down(st0, d); sq0 += __shfl_down(sq0, d);
    st1 += __shfl_down(st1, d); sq1 += __shfl_down(sq1, d);
  }
  const int lane = threadIdx.x & 63, wave = threadIdx.x >> 6;
  if (lane == 0) { red[wave][0] = st0; red[wave][1] = sq0; red[wave][2] = st1; red[wave][3] = sq1; }
  __syncthreads();
  if (threadIdx.x == 0) {
    float rs0 = 0, rq0 = 0, rsx1 = 0, rq1 = 0;
#pragma unroll
    for (int wv = 0; wv < 4; ++wv) {
      rs0 += red[wv][0]; rq0 += red[wv][1]; rsx1 += red[wv][2]; rq1 += red[wv][3];
    }
    float* pp = partials + (size_t)blockIdx.x * 4;
    pp[0] = rs0; pp[1] = rq0; pp[2] = rsx1; pp[3] = rq1;
  }
}

// kB: per-row stats finalize + out = sA*x*g + off (NCB=64 partials per row).
__global__ __launch_bounds__(256) void k_out(
    const float* __restrict__ x, const float* __restrict__ gain,
    const float* __restrict__ partials,
    const float* __restrict__ dc_w, const float* __restrict__ gamma,
    const float* __restrict__ beta, float* __restrict__ out) {
  __shared__ float stm[4];
  const int b = blockIdx.x >> 7;   // 128 blocks per batch row
  const int tid = threadIdx.x;
  float s0 = 0.f, q0 = 0.f, s1 = 0.f, q1 = 0.f;
  if (tid < NCB) {   // 64 chunk partials per row (one full wave)
    const float* pp = partials + (size_t)(b * NCB + tid) * 4;
    s0 = pp[0]; q0 = pp[1]; s1 = pp[2]; q1 = pp[3];
  }
#pragma unroll
  for (int d = 32; d > 0; d >>= 1) {
    s0 += __shfl_down(s0, d); q0 += __shfl_down(q0, d);
    s1 += __shfl_down(s1, d); q1 += __shfl_down(q1, d);
  }
  if (tid == 0) {
    const float m0 = s0 / (float)Tt, m1 = s1 / (float)Tt;
    const float v0 = q0 / (float)Tt - m0 * m0;
    const float v1 = q1 / (float)Tt - m1 * m1;
    const float dw0 = dc_w[0], dw1 = dc_w[1];
    const float sA0 = gamma[0] * dw0 / sqrtf(fmaf(dw0 * dw0, v0, 1e-5f));
    const float sA1 = gamma[1] * dw1 / sqrtf(fmaf(dw1 * dw1, v1, 1e-5f));
    stm[0] = sA0; stm[1] = beta[0] - sA0 * m0;   // dc_b cancels in layernorm
    stm[2] = sA1; stm[3] = beta[1] - sA1 * m1;
  }
  __syncthreads();
  const float sA0 = stm[0], off0 = stm[1], sA1 = stm[2], off1 = stm[3];
  const int t = (((blockIdx.x & 127) << 8) + tid) << 2;
  const float4 g = *(const float4*)(gain + (size_t)b * Tt + t);
  {
    const size_t o = (size_t)(b * 2 + 0) * Tt + t;
    const float4 xv = *(const float4*)(x + o);
    float4 ov;
    ov.x = fmaf(sA0 * g.x, xv.x, off0);
    ov.y = fmaf(sA0 * g.y, xv.y, off0);
    ov.z = fmaf(sA0 * g.z, xv.z, off0);
    ov.w = fmaf(sA0 * g.w, xv.w, off0);
    *(float4*)(out + o) = ov;
  }
  {
    const size_t o = (size_t)(b * 2 + 1) * Tt + t;
    const float4 xv = *(const float4*)(x + o);
    float4 ov;
    ov.x = fmaf(sA1 * g.x, xv.x, off1);
    ov.y = fmaf(sA1 * g.y, xv.y, off1);
    ov.z = fmaf(sA1 * g.z, xv.z, off1);
    ov.w = fmaf(sA1 * g.w, xv.w, off1);
    *(float4*)(out + o) = ov;
  }
}

extern "C" void kernel_launch(void* const* d_in, const int* in_sizes, int n_in,
                              void* d_out, int out_size, void* d_ws, size_t ws_size,
                              hipStream_t stream) {
  const float* x         = (const float*)d_in[0];
  const float* conv_w    = (const float*)d_in[1];
  const float* combine_w = (const float*)d_in[2];
  const float* combine_b = (const float*)d_in[3];
  const float* la_att    = (const float*)d_in[4];
  const float* la_rel    = (const float*)d_in[5];
  const float* dc_w      = (const float*)d_in[6];
  const float* gamma     = (const float*)d_in[8];
  const float* beta      = (const float*)d_in[9];
  float* out = (float*)d_out;
  float* ws = (float*)d_ws;

  float* pg       = ws;                    // Bb*Tt floats: gain
  float* partials = ws + (size_t)Bb * Tt;  // Bb*NCB*4

  hipLaunchKernelGGL(k_gain, dim3(Bb * NCB), dim3(TPB), 0, stream,
                     x, conv_w, combine_w, combine_b, la_att, la_rel, pg, partials);
  hipLaunchKernelGGL(k_out, dim3(Bb * 128), dim3(256), 0, stream,
                     x, pg, partials, dc_w, gamma, beta, out);
}

// Round 16
// 69.521 us; speedup vs baseline: 1.0986x; 1.0986x over previous
//
#include <hip/hip_runtime.h>
#include <math.h>

#define Bb 32
#define Tt 131072
#define SEG 4096          // segment per pass (lookback and emit are both 4096)
#define NCB (Tt / SEG)    // 32 chunks per row -> grid 1024 (4 blocks/CU)
#define TPB 256
#define PT 16             // SEG / TPB

// padded LDS index: +1 float per 16 -> inter-lane stride 17 (conflict-free)
#define PIDX(j) ((j) + ((j) >> 4))
#define XSP (PIDX(SEG + 64) + 8)

__device__ __forceinline__ float sigmoidf_(float v) { return 1.0f / (1.0f + __expf(-v)); }
__device__ __forceinline__ float softplusf_(float z) {
  return fmaxf(z, 0.0f) + __logf(1.0f + __expf(-fabsf(z)));
}
// sa >= 1e-8 here, so 1/(sqrt(sa)+1e-8) == rsqrt(sa) within 1e-4 rel; clamp coincides.
__device__ __forceinline__ float dgainf_(float sa) {
  return fminf(1000.0f, rsqrtf(sa));
}
__device__ __forceinline__ float pow16f_(float r) {
  float r2 = r * r, r4 = r2 * r2, r8 = r4 * r4;
  return r8 * r8;
}

// 4-wave block scan of affine maps s -> m*s + b (thread order = time order).
__device__ __forceinline__ void affine_scan4(
    float m, float b, float& Mex, float& Bex, float& Btot, float* smem) {
  const int lane = threadIdx.x & 63;
  const int wave = threadIdx.x >> 6;
  float mi = m, bi = b;
#pragma unroll
  for (int d = 1; d < 64; d <<= 1) {
    float mp = __shfl_up(mi, d);
    float bp = __shfl_up(bi, d);
    if (lane >= d) { bi = fmaf(mi, bp, bi); mi *= mp; }
  }
  __syncthreads();
  if (lane == 63) { smem[2 * wave] = mi; smem[2 * wave + 1] = bi; }
  __syncthreads();
  float Mw = 1.0f, Bw = 0.0f;
#pragma unroll
  for (int wv = 0; wv < 3; ++wv) {
    if (wv < wave) {
      float mw = smem[2 * wv], bw = smem[2 * wv + 1];
      Bw = fmaf(mw, Bw, bw);
      Mw = mw * Mw;
    }
  }
  float mep = __shfl_up(mi, 1);
  float bep = __shfl_up(bi, 1);
  float me = (lane == 0) ? 1.0f : mep;
  float be = (lane == 0) ? 0.0f : bep;
  Mex = me * Mw;
  Bex = fmaf(me, Bw, be);
  Btot = fmaf(mi, Bw, bi);   // block-inclusive total on thread TPB-1
}

// Stage x^2 for BOTH channels in one pass (one barrier outside).
__device__ __forceinline__ void stage2(
    const float* __restrict__ xr0, const float* __restrict__ xr1,
    float* xs0, float* xs1, const int t0) {
  for (int i = threadIdx.x; i < (SEG + 64) / 4; i += TPB) {
    const int g = t0 - 64 + 4 * i;   // raw lds[j] = x^2[t0-64+j]
    float4 a = make_float4(0.f, 0.f, 0.f, 0.f);
    float4 b = make_float4(0.f, 0.f, 0.f, 0.f);
    if (g >= 0) {
      a = *(const float4*)(xr0 + g);
      b = *(const float4*)(xr1 + g);
    }
    const int j = 4 * i;
    xs0[PIDX(j + 0)] = a.x * a.x;
    xs0[PIDX(j + 1)] = a.y * a.y;
    xs0[PIDX(j + 2)] = a.z * a.z;
    xs0[PIDX(j + 3)] = a.w * a.w;
    xs1[PIDX(j + 0)] = b.x * b.x;
    xs1[PIDX(j + 1)] = b.y * b.y;
    xs1[PIDX(j + 2)] = b.z * b.z;
    xs1[PIDX(j + 3)] = b.w * b.w;
  }
}

// Conv core on pre-squared LDS: 64 taps, 16-wide group prefetch (R12-proven
// shape). Weights pre-folded in global -> s_load -> SGPR operand of the FMA.
__device__ __forceinline__ void conv_core(
    const float* __restrict__ wf, const float* xs, float (&pacc)[PT], const int pb) {
  float win[16];
#pragma unroll
  for (int i = 0; i < 16; ++i) win[i] = xs[pb + 1 + i + ((1 + i) >> 4)];
#pragma unroll 1
  for (int g = 0; g < 4; ++g) {
    const int rb = pb + 17 * g + 18;   // padded addr of raw slot 16g+17
    float nxt[16];
#pragma unroll
    for (int j = 0; j < 16; ++j)
      if (g * 16 + j < 63) nxt[j] = xs[rb + j + ((j + 1) >> 4)];
#pragma unroll
    for (int k2 = 0; k2 < 16; ++k2) {
      const float wk = wf[g * 16 + k2];   // uniform -> scalar load (SGPR)
#pragma unroll
      for (int i = 0; i < PT; ++i)
        pacc[i] = fmaf(wk, win[(k2 + i) & 15], pacc[i]);
      win[k2] = nxt[k2];   // register move
    }
  }
}

// k_fold: wf[c*64+k] = conv_w[c][k] * combine_w[c]  (128 floats into ws)
__global__ void k_fold(const float* __restrict__ conv_w,
                       const float* __restrict__ combine_w, float* __restrict__ wf) {
  const int i = threadIdx.x;
  if (i < 128) wf[i] = conv_w[i] * combine_w[i >> 6];
}

// kA: per 4096-chunk: full 4096 lookback (zero-init, decay-exact: r1^4096==0,
// r2^4096~1.2e-9) + emitted 4096 segment.
__global__ __launch_bounds__(TPB, 3) void k_gain(
    const float* __restrict__ x, const float* __restrict__ wf,
    const float* __restrict__ combine_b,
    const float* __restrict__ la_att, const float* __restrict__ la_rel,
    float* __restrict__ pg, float* __restrict__ partials) {
  __shared__ float xs0[XSP];
  __shared__ float xs1[XSP];
  __shared__ float ssm[8];
  __shared__ float bc[3];
  __shared__ float red[4][4];
  const int b = blockIdx.x / NCB;
  const int ch = blockIdx.x % NCB;
  const int tc = ch * SEG;
  const int pb = 17 * (int)threadIdx.x;   // padded base of raw 16*tid
  const float a1 = sigmoidf_(la_att[0]); const float r1 = 1.0f - a1;
  const float a2 = sigmoidf_(la_rel[0]); const float r2 = 1.0f - a2;
  const float rs1 = __expf((float)SEG * __logf(r1));   // r1^4096 (underflows to 0)
  const float rs2 = __expf((float)SEG * __logf(r2));   // r2^4096 ~ 1.2e-9
  const float cb = combine_b[0];
  const float* xr0 = x + (size_t)(b * 2 + 0) * Tt;
  const float* xr1 = x + (size_t)(b * 2 + 1) * Tt;
  float s1 = 0.0f, s2 = 0.0f;    // EMA states entering current segment
  float st0 = 0.f, sq0 = 0.f, st1 = 0.f, sq1 = 0.f;

  const int s_begin = (ch == 0) ? 0 : -1;
#pragma unroll 1
  for (int s = s_begin; s <= 0; ++s) {
    const int t0 = tc + s * SEG;
    const bool emit = (s == 0);
    stage2(xr0, xr1, xs0, xs1, t0);
    __syncthreads();
    float xa[PT], xb[PT];
    if (emit) {
      // own raw x straight from global (L2-hot: same lines just staged);
      // issued before the conv so latency hides under the FMA stream.
#pragma unroll
      for (int i = 0; i < PT; i += 4) {
        *(float4*)(xa + i) = *(const float4*)(xr0 + t0 + (int)threadIdx.x * PT + i);
        *(float4*)(xb + i) = *(const float4*)(xr1 + t0 + (int)threadIdx.x * PT + i);
      }
    }
    float pacc[PT];
#pragma unroll
    for (int i = 0; i < PT; ++i) pacc[i] = cb;
    conv_core(wf, xs0, pacc, pb);
    conv_core(wf + 64, xs1, pacc, pb);
    float pv[PT];
#pragma unroll
    for (int i = 0; i < PT; ++i) pv[i] = softplusf_(pacc[i]) + 1e-8f;
    const bool init0 = (ch == 0) && emit;
    if (init0 && threadIdx.x == 0) bc[2] = pv[0];   // p[b,0]; visible after scan syncs
    float e1 = 0.0f;
#pragma unroll
    for (int i = 0; i < PT; ++i) e1 = fmaf(a1, pv[i], r1 * e1);
    float Mex, Bex, Bt;
    affine_scan4(pow16f_(r1), e1, Mex, Bex, Bt, ssm);
    if (init0) { s1 = bc[2]; s2 = dgainf_(bc[2]); }   // ref init: y[-1]=p0, g[-1]=dg(p0)
    float y = fmaf(Mex, s1, Bex);
    float dg[PT];
    float e2 = 0.0f;
#pragma unroll
    for (int i = 0; i < PT; ++i) {
      y = fmaf(a1, pv[i], r1 * y);
      dg[i] = dgainf_(y);
      e2 = fmaf(a2, dg[i], r2 * e2);
    }
    const float Bt1 = Bt;
    affine_scan4(pow16f_(r2), e2, Mex, Bex, Bt, ssm);
    if (threadIdx.x == TPB - 1) { bc[0] = Bt1; bc[1] = Bt; }
    if (emit) {
      float g = fmaf(Mex, s2, Bex);
      float gv[PT];
#pragma unroll
      for (int i = 0; i < PT; ++i) { g = fmaf(a2, dg[i], r2 * g); gv[i] = g; }
      float* prow = pg + (size_t)b * Tt + t0 + (int)threadIdx.x * PT;
#pragma unroll
      for (int i = 0; i < PT; i += 4)
        *(float4*)(prow + i) = make_float4(gv[i], gv[i + 1], gv[i + 2], gv[i + 3]);
#pragma unroll
      for (int i = 0; i < PT; ++i) {
        float u0 = xa[i] * gv[i]; st0 += u0; sq0 = fmaf(u0, u0, sq0);
        float u1 = xb[i] * gv[i]; st1 += u1; sq1 = fmaf(u1, u1, sq1);
      }
    }
    __syncthreads();   // bc[0..1] published; xs reads done before next staging
    s1 = fmaf(rs1, s1, bc[0]);
    s2 = fmaf(rs2, s2, bc[1]);
  }
  // block stats reduce -> partials[blockIdx.x]
#pragma unroll
  for (int d = 32; d > 0; d >>= 1) {
    st0 += __shfl_down(st0, d); sq0 += __shfl_down(sq0, d);
    st1 += __shfl_down(st1, d); sq1 += __shfl_down(sq1, d);
  }
  const int lane = threadIdx.x & 63, wave = threadIdx.x >> 6;
  if (lane == 0) { red[wave][0] = st0; red[wave][1] = sq0; red[wave][2] = st1; red[wave][3] = sq1; }
  __syncthreads();
  if (threadIdx.x == 0) {
    float rs0 = 0, rq0 = 0, rsx1 = 0, rq1 = 0;
#pragma unroll
    for (int wv = 0; wv < 4; ++wv) {
      rs0 += red[wv][0]; rq0 += red[wv][1]; rsx1 += red[wv][2]; rq1 += red[wv][3];
    }
    float* pp = partials + (size_t)blockIdx.x * 4;
    pp[0] = rs0; pp[1] = rq0; pp[2] = rsx1; pp[3] = rq1;
  }
}

// kB: per-row stats finalize + out = sA*x*g + off (NCB=32 partials per row).
__global__ __launch_bounds__(256) void k_out(
    const float* __restrict__ x, const float* __restrict__ gain,
    const float* __restrict__ partials,
    const float* __restrict__ dc_w, const float* __restrict__ gamma,
    const float* __restrict__ beta, float* __restrict__ out) {
  __shared__ float stm[4];
  const int b = blockIdx.x >> 7;   // 128 blocks per batch row
  const int tid = threadIdx.x;
  float s0 = 0.f, q0 = 0.f, s1 = 0.f, q1 = 0.f;
  if (tid < NCB) {
    const float* pp = partials + (size_t)(b * NCB + tid) * 4;
    s0 = pp[0]; q0 = pp[1]; s1 = pp[2]; q1 = pp[3];
  }
#pragma unroll
  for (int d = 16; d > 0; d >>= 1) {
    s0 += __shfl_down(s0, d); q0 += __shfl_down(q0, d);
    s1 += __shfl_down(s1, d); q1 += __shfl_down(q1, d);
  }
  if (tid == 0) {
    const float m0 = s0 / (float)Tt, m1 = s1 / (float)Tt;
    const float v0 = q0 / (float)Tt - m0 * m0;
    const float v1 = q1 / (float)Tt - m1 * m1;
    const float dw0 = dc_w[0], dw1 = dc_w[1];
    const float sA0 = gamma[0] * dw0 / sqrtf(fmaf(dw0 * dw0, v0, 1e-5f));
    const float sA1 = gamma[1] * dw1 / sqrtf(fmaf(dw1 * dw1, v1, 1e-5f));
    stm[0] = sA0; stm[1] = beta[0] - sA0 * m0;   // dc_b cancels in layernorm
    stm[2] = sA1; stm[3] = beta[1] - sA1 * m1;
  }
  __syncthreads();
  const float sA0 = stm[0], off0 = stm[1], sA1 = stm[2], off1 = stm[3];
  const int t = (((blockIdx.x & 127) << 8) + tid) << 2;
  const float4 g = *(const float4*)(gain + (size_t)b * Tt + t);
  {
    const size_t o = (size_t)(b * 2 + 0) * Tt + t;
    const float4 xv = *(const float4*)(x + o);
    float4 ov;
    ov.x = fmaf(sA0 * g.x, xv.x, off0);
    ov.y = fmaf(sA0 * g.y, xv.y, off0);
    ov.z = fmaf(sA0 * g.z, xv.z, off0);
    ov.w = fmaf(sA0 * g.w, xv.w, off0);
    *(float4*)(out + o) = ov;
  }
  {
    const size_t o = (size_t)(b * 2 + 1) * Tt + t;
    const float4 xv = *(const float4*)(x + o);
    float4 ov;
    ov.x = fmaf(sA1 * g.x, xv.x, off1);
    ov.y = fmaf(sA1 * g.y, xv.y, off1);
    ov.z = fmaf(sA1 * g.z, xv.z, off1);
    ov.w = fmaf(sA1 * g.w, xv.w, off1);
    *(float4*)(out + o) = ov;
  }
}

extern "C" void kernel_launch(void* const* d_in, const int* in_sizes, int n_in,
                              void* d_out, int out_size, void* d_ws, size_t ws_size,
                              hipStream_t stream) {
  const float* x         = (const float*)d_in[0];
  const float* conv_w    = (const float*)d_in[1];
  const float* combine_w = (const float*)d_in[2];
  const float* combine_b = (const float*)d_in[3];
  const float* la_att    = (const float*)d_in[4];
  const float* la_rel    = (const float*)d_in[5];
  const float* dc_w      = (const float*)d_in[6];
  const float* gamma     = (const float*)d_in[8];
  const float* beta      = (const float*)d_in[9];
  float* out = (float*)d_out;
  float* ws = (float*)d_ws;

  float* pg       = ws;                        // Bb*Tt floats: gain
  float* partials = ws + (size_t)Bb * Tt;      // Bb*NCB*4
  float* wfold    = partials + Bb * NCB * 4;   // 128

  hipLaunchKernelGGL(k_fold, dim3(1), dim3(128), 0, stream, conv_w, combine_w, wfold);
  hipLaunchKernelGGL(k_gain, dim3(Bb * NCB), dim3(TPB), 0, stream,
                     x, wfold, combine_b, la_att, la_rel, pg, partials);
  hipLaunchKernelGGL(k_out, dim3(Bb * 128), dim3(256), 0, stream,
                     x, pg, partials, dc_w, gamma, beta, out);
}

// Round 17
// 48.686 us; speedup vs baseline: 1.5687x; 1.4279x over previous
//
#include <hip/hip_runtime.h>
#include <math.h>

#define Bb 32
#define Tt 131072
#define SEG 4096          // segment per pass (lookback and emit are both 4096)
#define NCB (Tt / SEG)    // 32 chunks per row -> grid 1024 (4 blocks/CU)
#define TPB 256
#define PT 16             // SEG / TPB

#define XQN 4224          // bf16 x^2 elements per channel (4184 needed + slack)
#define NF4 (XQN / 4)     // 1056 float4 staging slots per channel
#define WROW 104          // wtab row stride (odd*8: kills bank conflicts)
#define PIDX(j) ((j) + ((j) >> 4))
#define PWSN (PIDX(SEG - 1) + 16)   // padded p_lds floats (4366)

typedef float f32x4 __attribute__((ext_vector_type(4)));
typedef short bf16x8 __attribute__((ext_vector_type(8)));

__device__ __forceinline__ float sigmoidf_(float v) { return 1.0f / (1.0f + __expf(-v)); }
__device__ __forceinline__ float softplusf_(float z) {
  return fmaxf(z, 0.0f) + __logf(1.0f + __expf(-fabsf(z)));
}
__device__ __forceinline__ float dgainf_(float sa) {
  return fminf(1000.0f, rsqrtf(sa));   // sa >= 1e-8: matches ref within 1e-4
}
__device__ __forceinline__ float pow16f_(float r) {
  float r2 = r * r, r4 = r2 * r2, r8 = r4 * r4;
  return r8 * r8;
}
__device__ __forceinline__ unsigned short f2bf(float f) {   // RNE f32->bf16
  unsigned int u = __float_as_uint(f);
  unsigned int r = (u + 0x7FFFu + ((u >> 16) & 1u)) >> 16;
  return (unsigned short)r;
}

// 4-wave block scan of affine maps s -> m*s + b (thread order = time order).
__device__ __forceinline__ void affine_scan4(
    float m, float b, float& Mex, float& Bex, float& Btot, float* smem) {
  const int lane = threadIdx.x & 63;
  const int wave = threadIdx.x >> 6;
  float mi = m, bi = b;
#pragma unroll
  for (int d = 1; d < 64; d <<= 1) {
    float mp = __shfl_up(mi, d);
    float bp = __shfl_up(bi, d);
    if (lane >= d) { bi = fmaf(mi, bp, bi); mi *= mp; }
  }
  __syncthreads();
  if (lane == 63) { smem[2 * wave] = mi; smem[2 * wave + 1] = bi; }
  __syncthreads();
  float Mw = 1.0f, Bw = 0.0f;
#pragma unroll
  for (int wv = 0; wv < 3; ++wv) {
    if (wv < wave) {
      float mw = smem[2 * wv], bw = smem[2 * wv + 1];
      Bw = fmaf(mw, Bw, bw);
      Mw = mw * Mw;
    }
  }
  float mep = __shfl_up(mi, 1);
  float bep = __shfl_up(bi, 1);
  float me = (lane == 0) ? 1.0f : mep;
  float be = (lane == 0) ? 0.0f : bep;
  Mex = me * Mw;
  Bex = fmaf(me, Bw, be);
  Btot = fmaf(mi, Bw, bi);   // block-inclusive total on thread TPB-1
}

// kA: MFMA conv. Per 4096-chunk: full 4096 lookback (zero-init, decay-exact)
// + emitted 4096. conv(x^2,64tap) via Hankel-A x phase-B mfma_16x16x32_bf16.
__global__ __launch_bounds__(TPB, 3) void k_gain(
    const float* __restrict__ x, const float* __restrict__ conv_w,
    const float* __restrict__ combine_w, const float* __restrict__ combine_b,
    const float* __restrict__ la_att, const float* __restrict__ la_rel,
    float* __restrict__ pg, float* __restrict__ partials) {
  __shared__ unsigned short xsq[2 * XQN];   // bf16 x^2, per-channel halves
  __shared__ float pws[PWSN];               // p (padded); start doubles as wtab
  __shared__ float ssm[8];
  __shared__ float bc[3];
  __shared__ float red[4][4];
  const int tid = (int)threadIdx.x;
  const int lane = tid & 63;
  const int wave = tid >> 6;
  const int b = blockIdx.x / NCB;
  const int ch = blockIdx.x % NCB;
  const int tc = ch * SEG;
  const float a1 = sigmoidf_(la_att[0]); const float r1 = 1.0f - a1;
  const float a2 = sigmoidf_(la_rel[0]); const float r2 = 1.0f - a2;
  const float rs1 = __expf((float)SEG * __logf(r1));   // r1^4096 -> 0
  const float rs2 = __expf((float)SEG * __logf(r2));   // r2^4096 ~ 1.2e-9
  const float cb = combine_b[0];
  const float* xr0 = x + (size_t)(b * 2 + 0) * Tt;
  const float* xr1 = x + (size_t)(b * 2 + 1) * Tt;

  // ---- build phase-shifted weight table in (pws-aliased) LDS:
  // wtab[c][j][k'] = conv_w[c][k'-j-1]*combine_w[c] for k'-j-1 in [0,64), else 0
  unsigned short* wtab = (unsigned short*)pws;   // 2*16*104 = 3328 bf16
  for (int idx = tid; idx < 2 * 16 * WROW; idx += TPB) {
    const int c = idx / (16 * WROW);
    const int r = idx % (16 * WROW);
    const int j = r / WROW;
    const int kp = r % WROW;
    const int ks = kp - j - 1;
    float wv = (ks >= 0 && ks < 64 && kp < 96)
                   ? conv_w[c * 64 + ks] * combine_w[c] : 0.0f;
    wtab[idx] = f2bf(wv);
  }
  __syncthreads();
  // B-fragments (held in registers for the whole kernel):
  // lane holds B[k'=32q+8*(lane>>4)+jj][col=lane&15]
  const int wb = (lane & 15) * WROW + 8 * (lane >> 4);
  bf16x8 B00 = *(const bf16x8*)&wtab[wb + 0];
  bf16x8 B01 = *(const bf16x8*)&wtab[wb + 32];
  bf16x8 B02 = *(const bf16x8*)&wtab[wb + 64];
  bf16x8 B10 = *(const bf16x8*)&wtab[16 * WROW + wb + 0];
  bf16x8 B11 = *(const bf16x8*)&wtab[16 * WROW + wb + 32];
  bf16x8 B12 = *(const bf16x8*)&wtab[16 * WROW + wb + 64];
  __syncthreads();   // B-frags read before pws overwrites wtab

  const int abase = 8 * ((lane & 15) + (lane >> 4));   // A-frag element base
  float s1 = 0.0f, s2 = 0.0f;
  float st0 = 0.f, sq0 = 0.f, st1 = 0.f, sq1 = 0.f;

  const int s_begin = (ch == 0) ? 0 : -1;
#pragma unroll 1
  for (int s = s_begin; s <= 0; ++s) {
    const int t0 = tc + s * SEG;
    const bool emit = (s == 0);
    // ---- stage x^2 as bf16 (both channels; zero-fill outside [0,Tt))
#pragma unroll 1
    for (int c = 0; c < 2; ++c) {
      const float* xr = c ? xr1 : xr0;
      unsigned short* xd = xsq + c * XQN;
      for (int i = tid; i < NF4; i += TPB) {
        const int g = t0 - 64 + 4 * i;
        float4 v = make_float4(0.f, 0.f, 0.f, 0.f);
        if (g >= 0 && g <= Tt - 4) v = *(const float4*)(xr + g);
        unsigned int p0 = (unsigned int)f2bf(v.x * v.x) |
                          ((unsigned int)f2bf(v.y * v.y) << 16);
        unsigned int p1 = (unsigned int)f2bf(v.z * v.z) |
                          ((unsigned int)f2bf(v.w * v.w) << 16);
        *(uint2*)&xd[4 * i] = make_uint2(p0, p1);
      }
    }
    __syncthreads();
    float xa[PT], xb[PT];
    if (emit) {   // own raw x for stats (L2-hot), issued before the conv
#pragma unroll
      for (int i = 0; i < PT; i += 4) {
        *(float4*)(xa + i) = *(const float4*)(xr0 + t0 + tid * PT + i);
        *(float4*)(xb + i) = *(const float4*)(xr1 + t0 + tid * PT + i);
      }
    }
    // ---- MFMA conv: wave w handles macro-tiles m = 8w..8w+7 (128 outputs each)
#pragma unroll 1
    for (int mi = 0; mi < 8; ++mi) {
      const int m = wave * 8 + mi;
      const int eb = 128 * m + abase;
      f32x4 acc = {0.f, 0.f, 0.f, 0.f};
      bf16x8 a0 = *(const bf16x8*)&xsq[eb + 0];
      bf16x8 a1 = *(const bf16x8*)&xsq[eb + 32];
      bf16x8 a2 = *(const bf16x8*)&xsq[eb + 64];
      acc = __builtin_amdgcn_mfma_f32_16x16x32_bf16(a0, B00, acc, 0, 0, 0);
      acc = __builtin_amdgcn_mfma_f32_16x16x32_bf16(a1, B01, acc, 0, 0, 0);
      acc = __builtin_amdgcn_mfma_f32_16x16x32_bf16(a2, B02, acc, 0, 0, 0);
      a0 = *(const bf16x8*)&xsq[XQN + eb + 0];
      a1 = *(const bf16x8*)&xsq[XQN + eb + 32];
      a2 = *(const bf16x8*)&xsq[XQN + eb + 64];
      acc = __builtin_amdgcn_mfma_f32_16x16x32_bf16(a0, B10, acc, 0, 0, 0);
      acc = __builtin_amdgcn_mfma_f32_16x16x32_bf16(a1, B11, acc, 0, 0, 0);
      acc = __builtin_amdgcn_mfma_f32_16x16x32_bf16(a2, B12, acc, 0, 0, 0);
      // C[i][j] = out[t0+128m+8i+j]; canonical cols j<8 cover all outputs once.
      // lane holds col=lane&15, rows (lane>>4)*4+reg.
      if ((lane & 15) < 8) {
        const int v0 = 128 * m + 32 * (lane >> 4) + (lane & 15);
        pws[PIDX(v0 + 0)]  = acc[0];
        pws[PIDX(v0 + 8)]  = acc[1];
        pws[PIDX(v0 + 16)] = acc[2];
        pws[PIDX(v0 + 24)] = acc[3];
      }
    }
    __syncthreads();   // p visible to scan readers
    // ---- softplus + EMA scans (R12/R16-proven machinery)
    float pv[PT];
#pragma unroll
    for (int i = 0; i < PT; ++i)
      pv[i] = softplusf_(pws[17 * tid + i] + cb) + 1e-8f;
    const bool init0 = (ch == 0) && emit;
    if (init0 && tid == 0) bc[2] = pv[0];   // p[b,0]; visible after scan syncs
    float e1 = 0.0f;
#pragma unroll
    for (int i = 0; i < PT; ++i) e1 = fmaf(a1, pv[i], r1 * e1);
    float Mex, Bex, Bt;
    affine_scan4(pow16f_(r1), e1, Mex, Bex, Bt, ssm);
    if (init0) { s1 = bc[2]; s2 = dgainf_(bc[2]); }   // ref init y[-1]=p0
    float y = fmaf(Mex, s1, Bex);
    float dg[PT];
    float e2 = 0.0f;
#pragma unroll
    for (int i = 0; i < PT; ++i) {
      y = fmaf(a1, pv[i], r1 * y);
      dg[i] = dgainf_(y);
      e2 = fmaf(a2, dg[i], r2 * e2);
    }
    const float Bt1 = Bt;
    affine_scan4(pow16f_(r2), e2, Mex, Bex, Bt, ssm);
    if (tid == TPB - 1) { bc[0] = Bt1; bc[1] = Bt; }
    if (emit) {
      float g = fmaf(Mex, s2, Bex);
      float gv[PT];
#pragma unroll
      for (int i = 0; i < PT; ++i) { g = fmaf(a2, dg[i], r2 * g); gv[i] = g; }
      float* prow = pg + (size_t)b * Tt + t0 + tid * PT;
#pragma unroll
      for (int i = 0; i < PT; i += 4)
        *(float4*)(prow + i) = make_float4(gv[i], gv[i + 1], gv[i + 2], gv[i + 3]);
#pragma unroll
      for (int i = 0; i < PT; ++i) {
        float u0 = xa[i] * gv[i]; st0 += u0; sq0 = fmaf(u0, u0, sq0);
        float u1 = xb[i] * gv[i]; st1 += u1; sq1 = fmaf(u1, u1, sq1);
      }
    }
    __syncthreads();   // bc published; xsq/pws reads done before next iteration
    s1 = fmaf(rs1, s1, bc[0]);
    s2 = fmaf(rs2, s2, bc[1]);
  }
  // block stats reduce -> partials[blockIdx.x]
#pragma unroll
  for (int d = 32; d > 0; d >>= 1) {
    st0 += __shfl_down(st0, d); sq0 += __shfl_down(sq0, d);
    st1 += __shfl_down(st1, d); sq1 += __shfl_down(sq1, d);
  }
  if (lane == 0) { red[wave][0] = st0; red[wave][1] = sq0; red[wave][2] = st1; red[wave][3] = sq1; }
  __syncthreads();
  if (tid == 0) {
    float rs0 = 0, rq0 = 0, rsx1 = 0, rq1 = 0;
#pragma unroll
    for (int wv = 0; wv < 4; ++wv) {
      rs0 += red[wv][0]; rq0 += red[wv][1]; rsx1 += red[wv][2]; rq1 += red[wv][3];
    }
    float* pp = partials + (size_t)blockIdx.x * 4;
    pp[0] = rs0; pp[1] = rq0; pp[2] = rsx1; pp[3] = rq1;
  }
}

// kB: per-row stats finalize + out = sA*x*g + off (NCB=32 partials per row).
__global__ __launch_bounds__(256) void k_out(
    const float* __restrict__ x, const float* __restrict__ gain,
    const float* __restrict__ partials,
    const float* __restrict__ dc_w, const float* __restrict__ gamma,
    const float* __restrict__ beta, float* __restrict__ out) {
  __shared__ float stm[4];
  const int b = blockIdx.x >> 7;   // 128 blocks per batch row
  const int tid = threadIdx.x;
  float s0 = 0.f, q0 = 0.f, s1 = 0.f, q1 = 0.f;
  if (tid < NCB) {
    const float* pp = partials + (size_t)(b * NCB + tid) * 4;
    s0 = pp[0]; q0 = pp[1]; s1 = pp[2]; q1 = pp[3];
  }
#pragma unroll
  for (int d = 16; d > 0; d >>= 1) {
    s0 += __shfl_down(s0, d); q0 += __shfl_down(q0, d);
    s1 += __shfl_down(s1, d); q1 += __shfl_down(q1, d);
  }
  if (tid == 0) {
    const float m0 = s0 / (float)Tt, m1 = s1 / (float)Tt;
    const float v0 = q0 / (float)Tt - m0 * m0;
    const float v1 = q1 / (float)Tt - m1 * m1;
    const float dw0 = dc_w[0], dw1 = dc_w[1];
    const float sA0 = gamma[0] * dw0 / sqrtf(fmaf(dw0 * dw0, v0, 1e-5f));
    const float sA1 = gamma[1] * dw1 / sqrtf(fmaf(dw1 * dw1, v1, 1e-5f));
    stm[0] = sA0; stm[1] = beta[0] - sA0 * m0;   // dc_b cancels in layernorm
    stm[2] = sA1; stm[3] = beta[1] - sA1 * m1;
  }
  __syncthreads();
  const float sA0 = stm[0], off0 = stm[1], sA1 = stm[2], off1 = stm[3];
  const int t = (((blockIdx.x & 127) << 8) + tid) << 2;
  const float4 g = *(const float4*)(gain + (size_t)b * Tt + t);
  {
    const size_t o = (size_t)(b * 2 + 0) * Tt + t;
    const float4 xv = *(const float4*)(x + o);
    float4 ov;
    ov.x = fmaf(sA0 * g.x, xv.x, off0);
    ov.y = fmaf(sA0 * g.y, xv.y, off0);
    ov.z = fmaf(sA0 * g.z, xv.z, off0);
    ov.w = fmaf(sA0 * g.w, xv.w, off0);
    *(float4*)(out + o) = ov;
  }
  {
    const size_t o = (size_t)(b * 2 + 1) * Tt + t;
    const float4 xv = *(const float4*)(x + o);
    float4 ov;
    ov.x = fmaf(sA1 * g.x, xv.x, off1);
    ov.y = fmaf(sA1 * g.y, xv.y, off1);
    ov.z = fmaf(sA1 * g.z, xv.z, off1);
    ov.w = fmaf(sA1 * g.w, xv.w, off1);
    *(float4*)(out + o) = ov;
  }
}

extern "C" void kernel_launch(void* const* d_in, const int* in_sizes, int n_in,
                              void* d_out, int out_size, void* d_ws, size_t ws_size,
                              hipStream_t stream) {
  const float* x         = (const float*)d_in[0];
  const float* conv_w    = (const float*)d_in[1];
  const float* combine_w = (const float*)d_in[2];
  const float* combine_b = (const float*)d_in[3];
  const float* la_att    = (const float*)d_in[4];
  const float* la_rel    = (const float*)d_in[5];
  const float* dc_w      = (const float*)d_in[6];
  const float* gamma     = (const float*)d_in[8];
  const float* beta      = (const float*)d_in[9];
  float* out = (float*)d_out;
  float* ws = (float*)d_ws;

  float* pg       = ws;                    // Bb*Tt floats: gain
  float* partials = ws + (size_t)Bb * Tt;  // Bb*NCB*4

  hipLaunchKernelGGL(k_gain, dim3(Bb * NCB), dim3(TPB), 0, stream,
                     x, conv_w, combine_w, combine_b, la_att, la_rel, pg, partials);
  hipLaunchKernelGGL(k_out, dim3(Bb * 128), dim3(256), 0, stream,
                     x, pg, partials, dc_w, gamma, beta, out);
}

// Round 18
// 47.533 us; speedup vs baseline: 1.6067x; 1.0243x over previous
//
#include <hip/hip_runtime.h>
#include <math.h>

#define Bb 32
#define Tt 131072
#define SEG 4096          // segment per pass (lookback and emit are both 4096)
#define NCB (Tt / SEG)    // 32 chunks per row -> grid 1024 (4 blocks/CU)
#define TPB 256
#define PT 16             // SEG / TPB

#define XQN 4224          // bf16 x^2 elements per channel (4176 needed + slack)
#define NF4 (XQN / 4)     // 1056 float4 staging slots per channel
#define WROW 104          // wtab row stride (odd*8: kills bank conflicts)
#define PIDX(j) ((j) + ((j) >> 4))
#define PWSN (PIDX(SEG - 1) + 16)   // padded p_lds floats

typedef float f32x4 __attribute__((ext_vector_type(4)));
typedef short bf16x8 __attribute__((ext_vector_type(8)));

__device__ __forceinline__ float sigmoidf_(float v) { return 1.0f / (1.0f + __expf(-v)); }
__device__ __forceinline__ float softplusf_(float z) {
  return fmaxf(z, 0.0f) + __logf(1.0f + __expf(-fabsf(z)));
}
__device__ __forceinline__ float dgainf_(float sa) {
  return fminf(1000.0f, rsqrtf(sa));   // sa >= 1e-8: matches ref within 1e-4
}
__device__ __forceinline__ float pow16f_(float r) {
  float r2 = r * r, r4 = r2 * r2, r8 = r4 * r4;
  return r8 * r8;
}
__device__ __forceinline__ unsigned short f2bf(float f) {   // RNE f32->bf16
  unsigned int u = __float_as_uint(f);
  unsigned int r = (u + 0x7FFFu + ((u >> 16) & 1u)) >> 16;
  return (unsigned short)r;
}

// 4-wave block scan of affine maps s -> m*s + b (thread order = time order).
__device__ __forceinline__ void affine_scan4(
    float m, float b, float& Mex, float& Bex, float& Btot, float* smem) {
  const int lane = threadIdx.x & 63;
  const int wave = threadIdx.x >> 6;
  float mi = m, bi = b;
#pragma unroll
  for (int d = 1; d < 64; d <<= 1) {
    float mp = __shfl_up(mi, d);
    float bp = __shfl_up(bi, d);
    if (lane >= d) { bi = fmaf(mi, bp, bi); mi *= mp; }
  }
  __syncthreads();
  if (lane == 63) { smem[2 * wave] = mi; smem[2 * wave + 1] = bi; }
  __syncthreads();
  float Mw = 1.0f, Bw = 0.0f;
#pragma unroll
  for (int wv = 0; wv < 3; ++wv) {
    if (wv < wave) {
      float mw = smem[2 * wv], bw = smem[2 * wv + 1];
      Bw = fmaf(mw, Bw, bw);
      Mw = mw * Mw;
    }
  }
  float mep = __shfl_up(mi, 1);
  float bep = __shfl_up(bi, 1);
  float me = (lane == 0) ? 1.0f : mep;
  float be = (lane == 0) ? 0.0f : bep;
  Mex = me * Mw;
  Bex = fmaf(me, Bw, be);
  Btot = fmaf(mi, Bw, bi);   // block-inclusive total on thread TPB-1
}

// kA: MFMA conv (row-stride-16 Hankel tiles: 256 outputs per 16x16 C-tile).
// Per 4096-chunk: full 4096 lookback (zero-init, decay-exact) + emitted 4096.
__global__ __launch_bounds__(TPB, 3) void k_gain(
    const float* __restrict__ x, const float* __restrict__ conv_w,
    const float* __restrict__ combine_w, const float* __restrict__ combine_b,
    const float* __restrict__ la_att, const float* __restrict__ la_rel,
    float* __restrict__ pg, float* __restrict__ partials) {
  __shared__ unsigned short xsq[2 * XQN];   // bf16 x^2, per-channel halves
  __shared__ float pws[PWSN];               // p (padded); start doubles as wtab
  __shared__ float ssm[8];
  __shared__ float bc[3];
  __shared__ float red[4][4];
  const int tid = (int)threadIdx.x;
  const int lane = tid & 63;
  const int wave = tid >> 6;
  const int b = blockIdx.x / NCB;
  const int ch = blockIdx.x % NCB;
  const int tc = ch * SEG;
  const float a1 = sigmoidf_(la_att[0]); const float r1 = 1.0f - a1;
  const float a2 = sigmoidf_(la_rel[0]); const float r2 = 1.0f - a2;
  const float rs1 = __expf((float)SEG * __logf(r1));   // r1^4096 -> 0
  const float rs2 = __expf((float)SEG * __logf(r2));   // r2^4096 ~ 1.2e-9
  const float cb = combine_b[0];
  const float* xr0 = x + (size_t)(b * 2 + 0) * Tt;
  const float* xr1 = x + (size_t)(b * 2 + 1) * Tt;

  // ---- build phase-shifted weight table in (pws-aliased) LDS:
  // wtab[c][j][k'] = conv_w[c][k'-j-1]*combine_w[c] for k'-j-1 in [0,64), else 0
  unsigned short* wtab = (unsigned short*)pws;   // 2*16*104 = 3328 bf16
  for (int idx = tid; idx < 2 * 16 * WROW; idx += TPB) {
    const int c = idx / (16 * WROW);
    const int r = idx % (16 * WROW);
    const int j = r / WROW;
    const int kp = r % WROW;
    const int ks = kp - j - 1;
    float wv = (ks >= 0 && ks < 64 && kp < 96)
                   ? conv_w[c * 64 + ks] * combine_w[c] : 0.0f;
    wtab[idx] = f2bf(wv);
  }
  __syncthreads();
  // B-fragments (held in registers for the whole kernel):
  // lane holds B[k'=32q+8*(lane>>4)+jj][col=lane&15]  (R17-proven layout)
  const int wb = (lane & 15) * WROW + 8 * (lane >> 4);
  bf16x8 B00 = *(const bf16x8*)&wtab[wb + 0];
  bf16x8 B01 = *(const bf16x8*)&wtab[wb + 32];
  bf16x8 B02 = *(const bf16x8*)&wtab[wb + 64];
  bf16x8 B10 = *(const bf16x8*)&wtab[16 * WROW + wb + 0];
  bf16x8 B11 = *(const bf16x8*)&wtab[16 * WROW + wb + 32];
  bf16x8 B12 = *(const bf16x8*)&wtab[16 * WROW + wb + 64];
  __syncthreads();   // B-frags read before pws overwrites wtab

  // A-frag base within a macro-tile: row (lane&15) stride 16, k-octet (lane>>4)
  const int abase = 16 * (lane & 15) + 8 * (lane >> 4);
  float s1 = 0.0f, s2 = 0.0f;
  float st0 = 0.f, sq0 = 0.f, st1 = 0.f, sq1 = 0.f;

  const int s_begin = (ch == 0) ? 0 : -1;
#pragma unroll 1
  for (int s = s_begin; s <= 0; ++s) {
    const int t0 = tc + s * SEG;
    const bool emit = (s == 0);
    // ---- stage x^2 as bf16 (both channels; zero-fill outside [0,Tt))
#pragma unroll 1
    for (int c = 0; c < 2; ++c) {
      const float* xr = c ? xr1 : xr0;
      unsigned short* xd = xsq + c * XQN;
      for (int i = tid; i < NF4; i += TPB) {
        const int g = t0 - 64 + 4 * i;
        float4 v = make_float4(0.f, 0.f, 0.f, 0.f);
        if (g >= 0 && g <= Tt - 4) v = *(const float4*)(xr + g);
        unsigned int p0 = (unsigned int)f2bf(v.x * v.x) |
                          ((unsigned int)f2bf(v.y * v.y) << 16);
        unsigned int p1 = (unsigned int)f2bf(v.z * v.z) |
                          ((unsigned int)f2bf(v.w * v.w) << 16);
        *(uint2*)&xd[4 * i] = make_uint2(p0, p1);
      }
    }
    __syncthreads();
    float xa[PT], xb[PT];
    if (emit) {   // own raw x for stats (L2-hot), issued before the conv
#pragma unroll
      for (int i = 0; i < PT; i += 4) {
        *(float4*)(xa + i) = *(const float4*)(xr0 + t0 + tid * PT + i);
        *(float4*)(xb + i) = *(const float4*)(xr1 + t0 + tid * PT + i);
      }
    }
    // ---- MFMA conv: wave w handles macro-tiles m = 4w..4w+3 (256 outputs each)
#pragma unroll 1
    for (int mi = 0; mi < 4; ++mi) {
      const int m = wave * 4 + mi;
      const int eb = 256 * m + abase;
      f32x4 acc = {0.f, 0.f, 0.f, 0.f};
      bf16x8 a0 = *(const bf16x8*)&xsq[eb + 0];
      bf16x8 a1 = *(const bf16x8*)&xsq[eb + 32];
      bf16x8 a2 = *(const bf16x8*)&xsq[eb + 64];
      acc = __builtin_amdgcn_mfma_f32_16x16x32_bf16(a0, B00, acc, 0, 0, 0);
      acc = __builtin_amdgcn_mfma_f32_16x16x32_bf16(a1, B01, acc, 0, 0, 0);
      acc = __builtin_amdgcn_mfma_f32_16x16x32_bf16(a2, B02, acc, 0, 0, 0);
      a0 = *(const bf16x8*)&xsq[XQN + eb + 0];
      a1 = *(const bf16x8*)&xsq[XQN + eb + 32];
      a2 = *(const bf16x8*)&xsq[XQN + eb + 64];
      acc = __builtin_amdgcn_mfma_f32_16x16x32_bf16(a0, B10, acc, 0, 0, 0);
      acc = __builtin_amdgcn_mfma_f32_16x16x32_bf16(a1, B11, acc, 0, 0, 0);
      acc = __builtin_amdgcn_mfma_f32_16x16x32_bf16(a2, B12, acc, 0, 0, 0);
      // C[i][j] -> out[t0 + 256m + 16i + j]; lane: col j=lane&15, rows 4*(lane>>4)+r
      const int v0 = 256 * m + 64 * (lane >> 4) + (lane & 15);
      pws[PIDX(v0 + 0)]  = acc[0];
      pws[PIDX(v0 + 16)] = acc[1];
      pws[PIDX(v0 + 32)] = acc[2];
      pws[PIDX(v0 + 48)] = acc[3];
    }
    __syncthreads();   // p visible to scan readers
    // ---- softplus + EMA scans (R12/R17-proven machinery)
    float pv[PT];
#pragma unroll
    for (int i = 0; i < PT; ++i)
      pv[i] = softplusf_(pws[17 * tid + i] + cb) + 1e-8f;
    const bool init0 = (ch == 0) && emit;
    if (init0 && tid == 0) bc[2] = pv[0];   // p[b,0]; visible after scan syncs
    float e1 = 0.0f;
#pragma unroll
    for (int i = 0; i < PT; ++i) e1 = fmaf(a1, pv[i], r1 * e1);
    float Mex, Bex, Bt;
    affine_scan4(pow16f_(r1), e1, Mex, Bex, Bt, ssm);
    if (init0) { s1 = bc[2]; s2 = dgainf_(bc[2]); }   // ref init y[-1]=p0
    float y = fmaf(Mex, s1, Bex);
    float dg[PT];
    float e2 = 0.0f;
#pragma unroll
    for (int i = 0; i < PT; ++i) {
      y = fmaf(a1, pv[i], r1 * y);
      dg[i] = dgainf_(y);
      e2 = fmaf(a2, dg[i], r2 * e2);
    }
    const float Bt1 = Bt;
    affine_scan4(pow16f_(r2), e2, Mex, Bex, Bt, ssm);
    if (tid == TPB - 1) { bc[0] = Bt1; bc[1] = Bt; }
    if (emit) {
      float g = fmaf(Mex, s2, Bex);
      float gv[PT];
#pragma unroll
      for (int i = 0; i < PT; ++i) { g = fmaf(a2, dg[i], r2 * g); gv[i] = g; }
      float* prow = pg + (size_t)b * Tt + t0 + tid * PT;
#pragma unroll
      for (int i = 0; i < PT; i += 4)
        *(float4*)(prow + i) = make_float4(gv[i], gv[i + 1], gv[i + 2], gv[i + 3]);
#pragma unroll
      for (int i = 0; i < PT; ++i) {
        float u0 = xa[i] * gv[i]; st0 += u0; sq0 = fmaf(u0, u0, sq0);
        float u1 = xb[i] * gv[i]; st1 += u1; sq1 = fmaf(u1, u1, sq1);
      }
    }
    __syncthreads();   // bc published; xsq/pws reads done before next iteration
    s1 = fmaf(rs1, s1, bc[0]);
    s2 = fmaf(rs2, s2, bc[1]);
  }
  // block stats reduce -> partials[blockIdx.x]
#pragma unroll
  for (int d = 32; d > 0; d >>= 1) {
    st0 += __shfl_down(st0, d); sq0 += __shfl_down(sq0, d);
    st1 += __shfl_down(st1, d); sq1 += __shfl_down(sq1, d);
  }
  if (lane == 0) { red[wave][0] = st0; red[wave][1] = sq0; red[wave][2] = st1; red[wave][3] = sq1; }
  __syncthreads();
  if (tid == 0) {
    float rs0 = 0, rq0 = 0, rsx1 = 0, rq1 = 0;
#pragma unroll
    for (int wv = 0; wv < 4; ++wv) {
      rs0 += red[wv][0]; rq0 += red[wv][1]; rsx1 += red[wv][2]; rq1 += red[wv][3];
    }
    float* pp = partials + (size_t)blockIdx.x * 4;
    pp[0] = rs0; pp[1] = rq0; pp[2] = rsx1; pp[3] = rq1;
  }
}

// kB: per-row stats finalize + out = sA*x*g + off (NCB=32 partials per row).
__global__ __launch_bounds__(256) void k_out(
    const float* __restrict__ x, const float* __restrict__ gain,
    const float* __restrict__ partials,
    const float* __restrict__ dc_w, const float* __restrict__ gamma,
    const float* __restrict__ beta, float* __restrict__ out) {
  __shared__ float stm[4];
  const int b = blockIdx.x >> 7;   // 128 blocks per batch row
  const int tid = threadIdx.x;
  float s0 = 0.f, q0 = 0.f, s1 = 0.f, q1 = 0.f;
  if (tid < NCB) {
    const float* pp = partials + (size_t)(b * NCB + tid) * 4;
    s0 = pp[0]; q0 = pp[1]; s1 = pp[2]; q1 = pp[3];
  }
#pragma unroll
  for (int d = 16; d > 0; d >>= 1) {
    s0 += __shfl_down(s0, d); q0 += __shfl_down(q0, d);
    s1 += __shfl_down(s1, d); q1 += __shfl_down(q1, d);
  }
  if (tid == 0) {
    const float m0 = s0 / (float)Tt, m1 = s1 / (float)Tt;
    const float v0 = q0 / (float)Tt - m0 * m0;
    const float v1 = q1 / (float)Tt - m1 * m1;
    const float dw0 = dc_w[0], dw1 = dc_w[1];
    const float sA0 = gamma[0] * dw0 / sqrtf(fmaf(dw0 * dw0, v0, 1e-5f));
    const float sA1 = gamma[1] * dw1 / sqrtf(fmaf(dw1 * dw1, v1, 1e-5f));
    stm[0] = sA0; stm[1] = beta[0] - sA0 * m0;   // dc_b cancels in layernorm
    stm[2] = sA1; stm[3] = beta[1] - sA1 * m1;
  }
  __syncthreads();
  const float sA0 = stm[0], off0 = stm[1], sA1 = stm[2], off1 = stm[3];
  const int t = (((blockIdx.x & 127) << 8) + tid) << 2;
  const float4 g = *(const float4*)(gain + (size_t)b * Tt + t);
  {
    const size_t o = (size_t)(b * 2 + 0) * Tt + t;
    const float4 xv = *(const float4*)(x + o);
    float4 ov;
    ov.x = fmaf(sA0 * g.x, xv.x, off0);
    ov.y = fmaf(sA0 * g.y, xv.y, off0);
    ov.z = fmaf(sA0 * g.z, xv.z, off0);
    ov.w = fmaf(sA0 * g.w, xv.w, off0);
    *(float4*)(out + o) = ov;
  }
  {
    const size_t o = (size_t)(b * 2 + 1) * Tt + t;
    const float4 xv = *(const float4*)(x + o);
    float4 ov;
    ov.x = fmaf(sA1 * g.x, xv.x, off1);
    ov.y = fmaf(sA1 * g.y, xv.y, off1);
    ov.z = fmaf(sA1 * g.z, xv.z, off1);
    ov.w = fmaf(sA1 * g.w, xv.w, off1);
    *(float4*)(out + o) = ov;
  }
}

extern "C" void kernel_launch(void* const* d_in, const int* in_sizes, int n_in,
                              void* d_out, int out_size, void* d_ws, size_t ws_size,
                              hipStream_t stream) {
  const float* x         = (const float*)d_in[0];
  const float* conv_w    = (const float*)d_in[1];
  const float* combine_w = (const float*)d_in[2];
  const float* combine_b = (const float*)d_in[3];
  const float* la_att    = (const float*)d_in[4];
  const float* la_rel    = (const float*)d_in[5];
  const float* dc_w      = (const float*)d_in[6];
  const float* gamma     = (const float*)d_in[8];
  const float* beta      = (const float*)d_in[9];
  float* out = (float*)d_out;
  float* ws = (float*)d_ws;

  float* pg       = ws;                    // Bb*Tt floats: gain
  float* partials = ws + (size_t)Bb * Tt;  // Bb*NCB*4

  hipLaunchKernelGGL(k_gain, dim3(Bb * NCB), dim3(TPB), 0, stream,
                     x, conv_w, combine_w, combine_b, la_att, la_rel, pg, partials);
  hipLaunchKernelGGL(k_out, dim3(Bb * 128), dim3(256), 0, stream,
                     x, pg, partials, dc_w, gamma, beta, out);
}